// Round 17
// baseline (969.130 us; speedup 1.0000x reference)
//
#include <hip/hip_runtime.h>
#include <hip/hip_fp16.h>
#include <math.h>
#include <limits.h>

#define HH 8
#define CC 32
#define NEG 0.2f

struct __align__(8) half4 { __half2 a, b; };
typedef float f32x4 __attribute__((ext_vector_type(4)));

__device__ __forceinline__ int ldnt(const int* p){ return __builtin_nontemporal_load(p); }
__device__ __forceinline__ float ldntf(const float* p){ return __builtin_nontemporal_load(p); }
__device__ __forceinline__ int f2ord(float f){ int i=__float_as_int(f); return i>=0? i : i^0x7fffffff; }
__device__ __forceinline__ float ord2f(int i){ return __int_as_float(i>=0? i : i^0x7fffffff); }

__device__ __forceinline__ void edge_sd_nt(const int* __restrict__ ei, int e, int E, int& s, int& d){
  if(e < E){ s = ldnt(ei+e); d = ldnt(ei+E+e); } else { s = e-E; d = s; }
}

// ------------------- init: cnt=0, gmax[16]=INT_MIN -------------------
__global__ void k_init2(int* __restrict__ cnt, int* __restrict__ gmax, int N){
  int i = blockIdx.x*blockDim.x + threadIdx.x;
  if(i < N) cnt[i] = 0;
  if(i < 16) gmax[i] = INT_MIN;
}

__global__ void k_count(const int* __restrict__ ei, int E, int ET, int* __restrict__ cnt){
  int e = blockIdx.x*blockDim.x + threadIdx.x;
  if(e >= ET) return;
  int d = (e < E) ? ldnt(ei+E+e) : e-E;
  atomicAdd(&cnt[d], 1);
}

__global__ __launch_bounds__(256) void k_scan_block(const int* __restrict__ cnt,
                                                    int* __restrict__ off,
                                                    int* __restrict__ bsum, int N){
  int i = blockIdx.x*256 + threadIdx.x;
  int v = (i < N) ? cnt[i] : 0;
  int lane = threadIdx.x & 63;
  int incl = v;
  #pragma unroll
  for(int o=1;o<64;o<<=1){ int u = __shfl_up(incl,o); if(lane>=o) incl += u; }
  __shared__ int wsum[4];
  if(lane==63) wsum[threadIdx.x>>6] = incl;
  __syncthreads();
  int w = threadIdx.x>>6, wadd = 0;
  #pragma unroll
  for(int k=0;k<4;k++) if(k<w) wadd += wsum[k];
  if(i < N) off[i] = wadd + incl - v;
  if(threadIdx.x==255) bsum[blockIdx.x] = wadd + incl;
}

__global__ __launch_bounds__(256) void k_scan_bsum(int* __restrict__ bsum, int nb,
                                                   int* __restrict__ offN){
  int t = threadIdx.x;
  int v = (t < nb) ? bsum[t] : 0;
  int lane = t & 63;
  int incl = v;
  #pragma unroll
  for(int o=1;o<64;o<<=1){ int u = __shfl_up(incl,o); if(lane>=o) incl += u; }
  __shared__ int wsum[4];
  if(lane==63) wsum[t>>6] = incl;
  __syncthreads();
  int w = t>>6, wadd = 0;
  #pragma unroll
  for(int k=0;k<4;k++) if(k<w) wadd += wsum[k];
  if(t < nb) bsum[t] = wadd + incl - v;
  if(t == 255) *offN = wadd + incl;
}

__global__ void k_scan_add(int* __restrict__ off, const int* __restrict__ bsum,
                           int* __restrict__ cur, int N){
  int i = blockIdx.x*256 + threadIdx.x;
  if(i < N){ int v = off[i] + bsum[blockIdx.x]; off[i] = v; cur[i] = v; }
}

__global__ void k_scatter(const int* __restrict__ ei, int E, int ET,
                          const int* __restrict__ x,
                          int* __restrict__ cur, int* __restrict__ csr_src,
                          int* __restrict__ csr_xv){
  int e = blockIdx.x*blockDim.x + threadIdx.x;
  if(e >= ET) return;
  int s,d; edge_sd_nt(ei,e,E,s,d);
  int pos = atomicAdd(&cur[d], 1);
  csr_src[pos] = s;
  csr_xv[pos]  = x[s];
}

// ws_s[k,h] = sum_c W2[k, h*32+c] * att_s2[h,c]   (and ws_d)
__global__ __launch_bounds__(256) void k_ws(const float* __restrict__ W2,
                                            const float* __restrict__ att_s2,
                                            const float* __restrict__ att_d2,
                                            float* __restrict__ ws_s, float* __restrict__ ws_d){
  int k = threadIdx.x >> 3, h = threadIdx.x & 7;
  float ss = 0.f, dd = 0.f;
  for(int c=0;c<CC;c++){
    float w = W2[k*256 + h*CC + c];
    ss = fmaf(w, att_s2[h*CC+c], ss);
    dd = fmaf(w, att_d2[h*CC+c], dd);
  }
  ws_s[k*HH+h] = ss;
  ws_d[k*HH+h] = dd;
}

// ------------------- layer-1 vocab-space GEMM (+ gmax1 fold) -------------------
__global__ __launch_bounds__(256,4) void k_gemm1(
    const float* __restrict__ X, const float* __restrict__ W,
    const float* __restrict__ att_s, const float* __restrict__ att_d,
    __half* __restrict__ xl, float* __restrict__ a_src, float* __restrict__ a_dst,
    int* __restrict__ gmax1, int V){
  const int ROWS = 8, FIN = 128;
  __shared__ __align__(16) float xs[ROWS][FIN];
  __shared__ int smax[8];
  int row0 = blockIdx.x*ROWS;
  int tid = threadIdx.x;
  if(tid < 8) smax[tid] = INT_MIN;
  for(int p = tid; p < ROWS*FIN; p += 256){
    int r = p/FIN, kk = p - r*FIN;
    int row = row0 + r;
    xs[r][kk] = (row < V) ? ldntf(X + (size_t)row*FIN + kk) : 0.f;
  }
  __syncthreads();
  float acc[ROWS];
  #pragma unroll
  for(int r=0;r<ROWS;r++) acc[r]=0.f;
  for(int k=0;k<FIN;k++){
    float w = W[(size_t)k*256 + tid];
    #pragma unroll
    for(int r=0;r<ROWS;r++) acc[r] = fmaf(xs[r][k], w, acc[r]);
  }
  float as = att_s[tid], ad = att_d[tid];
  #pragma unroll
  for(int r=0;r<ROWS;r++){
    int n = row0+r;
    float v = acc[r];
    float ps = v*as, pd = v*ad;
    #pragma unroll
    for(int msk=16; msk>=1; msk>>=1){
      ps += __shfl_xor(ps, msk);
      pd += __shfl_xor(pd, msk);
    }
    if(n < V){
      xl[(size_t)n*256 + tid] = __float2half(v);
      if((tid&31)==0){
        int hh = tid>>5;
        a_src[n*HH+hh] = ps;
        a_dst[n*HH+hh] = pd;
        atomicMax(&smax[hh], f2ord(ps));
      }
    }
  }
  __syncthreads();
  if(tid < 8) atomicMax(&gmax1[tid], smax[tid]);
}

// ------------------- layer 1 fused: batched-ILP loop + full-wave epilogue (+gmax2 fold) ----
__global__ __launch_bounds__(256) void k_fused1(
    const int* __restrict__ off, const int* __restrict__ csr_xv,
    const int* __restrict__ x,
    const float* __restrict__ a_src_v, const float* __restrict__ a_dst_v,
    const int* __restrict__ gmax1,
    const __half* __restrict__ xl_v, const float* __restrict__ bias,
    const float* __restrict__ ws_s, const float* __restrict__ ws_d,
    __half* __restrict__ h2h, float* __restrict__ a_src2, float* __restrict__ a_dst2,
    int* __restrict__ gmax2, int N){
  __shared__ int smax[8];
  int wid = (int)((blockIdx.x*(size_t)blockDim.x + threadIdx.x) >> 6);
  int lane = threadIdx.x & 63;
  if(threadIdx.x < 8) smax[threadIdx.x] = INT_MIN;
  __syncthreads();
  const bool act = wid < N;
  const int h2 = lane >> 3, q = lane & 7, c0 = q*4;

  if(act){
    const int start = off[wid], end = off[wid+1];
    const int t = lane >> 3, h = lane & 7;
    const int xv_n = x[wid];
    const float ad = a_dst_v[xv_n*HH + h];
    float mb = ord2f(gmax1[h]) + ad;
    mb = mb > 0.f ? mb : NEG*mb;

    const __half* xp = xl_v + h2*CC + c0;   // head block at column h2*32 of 256-wide row

    int sv = ldnt(csr_xv + min(start + t, end-1));
    float sraw = a_src_v[sv*HH + h] + ad;
    bool valid = (start + t) < end;

    float eesum = 0.f;
    float4 acc = make_float4(0.f,0.f,0.f,0.f);
    for(int j0 = start; j0 < end; j0 += 8){
      int svn = 0; float srawn = 0.f; bool validn = false;
      if(j0 + 8 < end){
        int jjn = j0 + 8 + t;
        svn = ldnt(csr_xv + min(jjn, end-1));
        srawn = a_src_v[svn*HH + h] + ad;
        validn = jjn < end;
      }
      float v = sraw > 0.f ? sraw : NEG*sraw;
      float ee = valid ? __expf(v - mb) : 0.f;
      eesum += ee;
      float av[8];
      #pragma unroll
      for(int u=0;u<8;u++) av[u] = __shfl(ee, u*8 + h2);
      int s0 = __builtin_amdgcn_readlane(sv, 0);
      int s1 = __builtin_amdgcn_readlane(sv, 8);
      int s2 = __builtin_amdgcn_readlane(sv, 16);
      int s3 = __builtin_amdgcn_readlane(sv, 24);
      int s4 = __builtin_amdgcn_readlane(sv, 32);
      int s5 = __builtin_amdgcn_readlane(sv, 40);
      int s6 = __builtin_amdgcn_readlane(sv, 48);
      int s7 = __builtin_amdgcn_readlane(sv, 56);
      uint2 rv[8];
      rv[0] = *reinterpret_cast<const uint2*>(xp + (size_t)s0*256);
      rv[1] = *reinterpret_cast<const uint2*>(xp + (size_t)s1*256);
      rv[2] = *reinterpret_cast<const uint2*>(xp + (size_t)s2*256);
      rv[3] = *reinterpret_cast<const uint2*>(xp + (size_t)s3*256);
      rv[4] = *reinterpret_cast<const uint2*>(xp + (size_t)s4*256);
      rv[5] = *reinterpret_cast<const uint2*>(xp + (size_t)s5*256);
      rv[6] = *reinterpret_cast<const uint2*>(xp + (size_t)s6*256);
      rv[7] = *reinterpret_cast<const uint2*>(xp + (size_t)s7*256);
      #pragma unroll
      for(int u=0;u<8;u++){
        __half2 ha = *reinterpret_cast<__half2*>(&rv[u].x);
        __half2 hb = *reinterpret_cast<__half2*>(&rv[u].y);
        float2 f01 = __half22float2(ha), f23 = __half22float2(hb);
        acc.x = fmaf(av[u], f01.x, acc.x);
        acc.y = fmaf(av[u], f01.y, acc.y);
        acc.z = fmaf(av[u], f23.x, acc.z);
        acc.w = fmaf(av[u], f23.y, acc.w);
      }
      sv = svn; sraw = srawn; valid = validn;
    }
    #pragma unroll
    for(int msk=8; msk<64; msk<<=1) eesum += __shfl_xor(eesum, msk);
    float is2 = 0.125f / __shfl(eesum, h2);
    acc.x *= is2; acc.y *= is2; acc.z *= is2; acc.w *= is2;
    #pragma unroll
    for(int msk=8; msk<64; msk<<=1){
      acc.x += __shfl_xor(acc.x, msk);
      acc.y += __shfl_xor(acc.y, msk);
      acc.z += __shfl_xor(acc.z, msk);
      acc.w += __shfl_xor(acc.w, msk);
    }
    // every lane now holds the reduced channel-quad q total (replicated across h2 groups)
    const float4 b = *reinterpret_cast<const float4*>(bias + c0);
    float4 o = make_float4(fmaxf(acc.x+b.x,0.f), fmaxf(acc.y+b.y,0.f),
                           fmaxf(acc.z+b.z,0.f), fmaxf(acc.w+b.w,0.f));
    if(lane < 8){
      half4 hv;
      hv.a = __floats2half2_rn(o.x, o.y);
      hv.b = __floats2half2_rn(o.z, o.w);
      *reinterpret_cast<half4*>(h2h + (size_t)wid*CC + c0) = hv;
    }
    // layer-2 scores across all 64 lanes: lane (h2,q) -> head h2 partial over k = 4q..4q+3
    float ps = 0.f, pd = 0.f;
    ps = fmaf(o.x, ws_s[(4*q+0)*HH + h2], ps);
    ps = fmaf(o.y, ws_s[(4*q+1)*HH + h2], ps);
    ps = fmaf(o.z, ws_s[(4*q+2)*HH + h2], ps);
    ps = fmaf(o.w, ws_s[(4*q+3)*HH + h2], ps);
    pd = fmaf(o.x, ws_d[(4*q+0)*HH + h2], pd);
    pd = fmaf(o.y, ws_d[(4*q+1)*HH + h2], pd);
    pd = fmaf(o.z, ws_d[(4*q+2)*HH + h2], pd);
    pd = fmaf(o.w, ws_d[(4*q+3)*HH + h2], pd);
    #pragma unroll
    for(int msk=1; msk<8; msk<<=1){
      ps += __shfl_xor(ps, msk);
      pd += __shfl_xor(pd, msk);
    }
    if(q == 0){
      a_src2[wid*HH + h2] = ps;
      a_dst2[wid*HH + h2] = pd;
      atomicMax(&smax[h2], f2ord(ps));
    }
  }
  __syncthreads();
  if(threadIdx.x < 8) atomicMax(&gmax2[threadIdx.x], smax[threadIdx.x]);
}

// ------------------- layer 2 fused: batched-ILP agg + in-kernel W2 transform ----
__global__ __launch_bounds__(256) void k_fused2(
    const int* __restrict__ off, const int* __restrict__ csr_src,
    const float* __restrict__ a_src2, const float* __restrict__ a_dst2,
    const int* __restrict__ gmax2,
    const __half* __restrict__ h2h, const float* __restrict__ W2,
    const float* __restrict__ b2, float* __restrict__ z, int N){
  __shared__ __align__(16) float aggl[4][256];
  int w = threadIdx.x >> 6, lane = threadIdx.x & 63;
  int wid = (int)(blockIdx.x*4 + w);
  const bool act = wid < N;
  const int h2 = lane >> 3, k0 = (lane & 7)*4;
  f32x4 oo = {0.f,0.f,0.f,0.f};

  if(act){
    const int start = off[wid], end = off[wid+1];
    const int t = lane >> 3, h = lane & 7;
    const float ad = a_dst2[wid*HH + h];
    float mb = ord2f(gmax2[h]) + ad;
    mb = mb > 0.f ? mb : NEG*mb;

    const __half* hp = h2h + k0;   // whole 32-ch row consumed per head; no h2 offset

    int sv = ldnt(csr_src + min(start + t, end-1));
    float sraw = a_src2[sv*HH + h] + ad;
    bool valid = (start + t) < end;

    float eesum = 0.f;
    float4 acc = make_float4(0.f,0.f,0.f,0.f);
    for(int j0 = start; j0 < end; j0 += 8){
      int svn = 0; float srawn = 0.f; bool validn = false;
      if(j0 + 8 < end){
        int jjn = j0 + 8 + t;
        svn = ldnt(csr_src + min(jjn, end-1));
        srawn = a_src2[svn*HH + h] + ad;
        validn = jjn < end;
      }
      float v = sraw > 0.f ? sraw : NEG*sraw;
      float ee = valid ? __expf(v - mb) : 0.f;
      eesum += ee;
      float av[8];
      #pragma unroll
      for(int u=0;u<8;u++) av[u] = __shfl(ee, u*8 + h2);
      int s0 = __builtin_amdgcn_readlane(sv, 0);
      int s1 = __builtin_amdgcn_readlane(sv, 8);
      int s2 = __builtin_amdgcn_readlane(sv, 16);
      int s3 = __builtin_amdgcn_readlane(sv, 24);
      int s4 = __builtin_amdgcn_readlane(sv, 32);
      int s5 = __builtin_amdgcn_readlane(sv, 40);
      int s6 = __builtin_amdgcn_readlane(sv, 48);
      int s7 = __builtin_amdgcn_readlane(sv, 56);
      uint2 rv[8];
      rv[0] = *reinterpret_cast<const uint2*>(hp + (size_t)s0*CC);
      rv[1] = *reinterpret_cast<const uint2*>(hp + (size_t)s1*CC);
      rv[2] = *reinterpret_cast<const uint2*>(hp + (size_t)s2*CC);
      rv[3] = *reinterpret_cast<const uint2*>(hp + (size_t)s3*CC);
      rv[4] = *reinterpret_cast<const uint2*>(hp + (size_t)s4*CC);
      rv[5] = *reinterpret_cast<const uint2*>(hp + (size_t)s5*CC);
      rv[6] = *reinterpret_cast<const uint2*>(hp + (size_t)s6*CC);
      rv[7] = *reinterpret_cast<const uint2*>(hp + (size_t)s7*CC);
      #pragma unroll
      for(int u=0;u<8;u++){
        __half2 ha = *reinterpret_cast<__half2*>(&rv[u].x);
        __half2 hb = *reinterpret_cast<__half2*>(&rv[u].y);
        float2 f01 = __half22float2(ha), f23 = __half22float2(hb);
        acc.x = fmaf(av[u], f01.x, acc.x);
        acc.y = fmaf(av[u], f01.y, acc.y);
        acc.z = fmaf(av[u], f23.x, acc.z);
        acc.w = fmaf(av[u], f23.y, acc.w);
      }
      sv = svn; sraw = srawn; valid = validn;
    }
    #pragma unroll
    for(int msk=8; msk<64; msk<<=1) eesum += __shfl_xor(eesum, msk);
    float is2 = 0.125f / __shfl(eesum, h2);
    oo.x = acc.x*is2; oo.y = acc.y*is2; oo.z = acc.z*is2; oo.w = acc.w*is2;
  }
  *reinterpret_cast<f32x4*>(&aggl[w][h2*CC + k0]) = oo;
  __syncthreads();

  // transform: z[n,ch] = sum_h sum_k agg[h][k] * W2[k, h*32+ch] + b2[ch]
  const int ch = lane & 31, part = lane >> 5;
  float p0=0.f, p1=0.f, p2=0.f, p3=0.f;
  #pragma unroll
  for(int hh = 0; hh < 4; ++hh){
    int hq = part*4 + hh;
    const float* wcol = W2 + hq*CC + ch;
    const float* a = &aggl[w][hq*CC];
    #pragma unroll
    for(int k=0;k<CC;k+=4){
      p0 = fmaf(a[k+0], wcol[(size_t)(k+0)*256], p0);
      p1 = fmaf(a[k+1], wcol[(size_t)(k+1)*256], p1);
      p2 = fmaf(a[k+2], wcol[(size_t)(k+2)*256], p2);
      p3 = fmaf(a[k+3], wcol[(size_t)(k+3)*256], p3);
    }
  }
  float p = (p0+p1)+(p2+p3);
  p += __shfl_xor(p, 32);
  if(act && part==0) z[(size_t)wid*CC + ch] = p + b2[ch];
}

__global__ void k_decode(const int* __restrict__ eli, int EL,
                         const float* __restrict__ z, float* __restrict__ out){
  int e = blockIdx.x*blockDim.x + threadIdx.x;
  if(e >= EL) return;
  const float4* za = reinterpret_cast<const float4*>(z + (size_t)ldnt(eli+e)*CC);
  const float4* zb = reinterpret_cast<const float4*>(z + (size_t)ldnt(eli+EL+e)*CC);
  float s = 0.f;
  #pragma unroll
  for(int j=0;j<8;j++){
    float4 u = za[j], v = zb[j];
    s += u.x*v.x + u.y*v.y + u.z*v.z + u.w*v.w;
  }
  out[e] = s;
}

extern "C" void kernel_launch(void* const* d_in, const int* in_sizes, int n_in,
                              void* d_out, int out_size, void* d_ws, size_t ws_size,
                              hipStream_t stream){
  const int*   x   = (const int*)d_in[0];
  const int*   ei  = (const int*)d_in[1];
  const int*   eli = (const int*)d_in[2];
  const float* emb = (const float*)d_in[3];
  const float* W1  = (const float*)d_in[4];
  const float* as1 = (const float*)d_in[5];
  const float* ad1 = (const float*)d_in[6];
  const float* b1  = (const float*)d_in[7];
  const float* W2  = (const float*)d_in[8];
  const float* as2 = (const float*)d_in[9];
  const float* ad2 = (const float*)d_in[10];
  const float* b2  = (const float*)d_in[11];

  const int N  = in_sizes[0];
  const int V  = in_sizes[3]/128;   // 5000
  const int E  = in_sizes[1]/2;
  const int EL = in_sizes[2]/2;
  const int ET = E + N;             // edges + self-loops

  // ---- workspace layout ----
  __half* xl_v = (__half*)d_ws;                         // V*256 halves
  __half* h2h  = xl_v + (size_t)V*256;                  // N*32 halves
  float* a_src_v = (float*)(h2h + (size_t)N*CC);        // V*8
  float* a_dst_v = a_src_v + (size_t)V*HH;              // V*8
  float* a_src2  = a_dst_v + (size_t)V*HH;              // N*8
  float* a_dst2  = a_src2 + (size_t)N*HH;               // N*8
  float* z       = a_dst2 + (size_t)N*HH;               // N*32
  float* ws_s    = z + (size_t)N*CC;                    // 256
  float* ws_d    = ws_s + 256;                          // 256
  int*   gmax1   = (int*)(ws_d + 256);                  // 8
  int*   gmax2   = gmax1 + 8;                           // 8
  int*   cnt   = gmax2 + 8;                             // N
  int*   off   = cnt + N;                               // N+1
  int*   cur   = off + N + 1;                           // N
  int*   bsum  = cur + N;                               // cdiv(N,256)
  int*   csr   = bsum + ((N+255)/256);                  // ET
  int*   csr_xv= csr + ET;                              // ET

  dim3 blk(256);
  auto cdiv = [](long long a, long long b){ return (unsigned)((a+b-1)/b); };
  const int nb = (int)cdiv(N,256);

  // ---- CSR build ----
  k_init2<<<cdiv(N,256), blk, 0, stream>>>(cnt, gmax1, N);
  k_count<<<cdiv(ET,256), blk, 0, stream>>>(ei, E, ET, cnt);
  k_scan_block<<<nb, blk, 0, stream>>>(cnt, off, bsum, N);
  k_scan_bsum<<<1, blk, 0, stream>>>(bsum, nb, off + N);
  k_scan_add<<<nb, blk, 0, stream>>>(off, bsum, cur, N);
  k_scatter<<<cdiv(ET,256), blk, 0, stream>>>(ei, E, ET, x, cur, csr, csr_xv);

  // ---- small precomputes ----
  k_ws<<<1, blk, 0, stream>>>(W2, as2, ad2, ws_s, ws_d);

  // ---- layer 1 (vocab space); gmax2 computed in-epilogue ----
  k_gemm1<<<cdiv(V,8), blk, 0, stream>>>(emb, W1, as1, ad1, xl_v, a_src_v, a_dst_v, gmax1, V);
  k_fused1<<<cdiv((long long)N*64,256), blk, 0, stream>>>(off, csr_xv, x, a_src_v, a_dst_v,
                                                          gmax1, xl_v, b1, ws_s, ws_d,
                                                          h2h, a_src2, a_dst2, gmax2, N);

  // ---- layer 2 (agg + transform fused) ----
  k_fused2<<<cdiv(N,4), blk, 0, stream>>>(off, csr, a_src2, a_dst2,
                                          gmax2, h2h, W2, b2, z, N);

  // ---- decode ----
  k_decode<<<cdiv(EL,256), blk, 0, stream>>>(eli, EL, z, (float*)d_out);
}

// Round 18
// 337.235 us; speedup vs baseline: 2.8738x; 2.8738x over previous
//
#include <hip/hip_runtime.h>
#include <hip/hip_fp16.h>
#include <math.h>
#include <limits.h>

#define HH 8
#define CC 32
#define NEG 0.2f

struct __align__(8) half4 { __half2 a, b; };
typedef float f32x4 __attribute__((ext_vector_type(4)));

__device__ __forceinline__ int ldnt(const int* p){ return __builtin_nontemporal_load(p); }
__device__ __forceinline__ float ldntf(const float* p){ return __builtin_nontemporal_load(p); }
__device__ __forceinline__ f32x4 ldnt4(const float* p){ return __builtin_nontemporal_load((const f32x4*)p); }
__device__ __forceinline__ void stnt4(float* p, f32x4 v){ __builtin_nontemporal_store(v, (f32x4*)p); }
__device__ __forceinline__ int f2ord(float f){ int i=__float_as_int(f); return i>=0? i : i^0x7fffffff; }
__device__ __forceinline__ float ord2f(int i){ return __int_as_float(i>=0? i : i^0x7fffffff); }

__device__ __forceinline__ void edge_sd_nt(const int* __restrict__ ei, int e, int E, int& s, int& d){
  if(e < E){ s = ldnt(ei+e); d = ldnt(ei+E+e); } else { s = e-E; d = s; }
}

// ------------------- init: cnt=0, gmax[16]=INT_MIN -------------------
__global__ void k_init2(int* __restrict__ cnt, int* __restrict__ gmax, int N){
  int i = blockIdx.x*blockDim.x + threadIdx.x;
  if(i < N) cnt[i] = 0;
  if(i < 16) gmax[i] = INT_MIN;
}

__global__ void k_count(const int* __restrict__ ei, int E, int ET, int* __restrict__ cnt){
  int e = blockIdx.x*blockDim.x + threadIdx.x;
  if(e >= ET) return;
  int d = (e < E) ? ldnt(ei+E+e) : e-E;
  atomicAdd(&cnt[d], 1);
}

__global__ __launch_bounds__(256) void k_scan_block(const int* __restrict__ cnt,
                                                    int* __restrict__ off,
                                                    int* __restrict__ bsum, int N){
  int i = blockIdx.x*256 + threadIdx.x;
  int v = (i < N) ? cnt[i] : 0;
  int lane = threadIdx.x & 63;
  int incl = v;
  #pragma unroll
  for(int o=1;o<64;o<<=1){ int u = __shfl_up(incl,o); if(lane>=o) incl += u; }
  __shared__ int wsum[4];
  if(lane==63) wsum[threadIdx.x>>6] = incl;
  __syncthreads();
  int w = threadIdx.x>>6, wadd = 0;
  #pragma unroll
  for(int k=0;k<4;k++) if(k<w) wadd += wsum[k];
  if(i < N) off[i] = wadd + incl - v;
  if(threadIdx.x==255) bsum[blockIdx.x] = wadd + incl;
}

__global__ __launch_bounds__(256) void k_scan_bsum(int* __restrict__ bsum, int nb,
                                                   int* __restrict__ offN){
  int t = threadIdx.x;
  int v = (t < nb) ? bsum[t] : 0;
  int lane = t & 63;
  int incl = v;
  #pragma unroll
  for(int o=1;o<64;o<<=1){ int u = __shfl_up(incl,o); if(lane>=o) incl += u; }
  __shared__ int wsum[4];
  if(lane==63) wsum[t>>6] = incl;
  __syncthreads();
  int w = t>>6, wadd = 0;
  #pragma unroll
  for(int k=0;k<4;k++) if(k<w) wadd += wsum[k];
  if(t < nb) bsum[t] = wadd + incl - v;
  if(t == 255) *offN = wadd + incl;
}

__global__ void k_scan_add(int* __restrict__ off, const int* __restrict__ bsum,
                           int* __restrict__ cur, int N){
  int i = blockIdx.x*256 + threadIdx.x;
  if(i < N){ int v = off[i] + bsum[blockIdx.x]; off[i] = v; cur[i] = v; }
}

__global__ void k_scatter(const int* __restrict__ ei, int E, int ET,
                          const int* __restrict__ x,
                          int* __restrict__ cur, int* __restrict__ csr_src,
                          int* __restrict__ csr_xv){
  int e = blockIdx.x*blockDim.x + threadIdx.x;
  if(e >= ET) return;
  int s,d; edge_sd_nt(ei,e,E,s,d);
  int pos = atomicAdd(&cur[d], 1);
  csr_src[pos] = s;
  csr_xv[pos]  = x[s];
}

// ws_s[k,h] = sum_c W2[k, h*32+c] * att_s2[h,c]   (and ws_d)
__global__ __launch_bounds__(256) void k_ws(const float* __restrict__ W2,
                                            const float* __restrict__ att_s2,
                                            const float* __restrict__ att_d2,
                                            float* __restrict__ ws_s, float* __restrict__ ws_d){
  int k = threadIdx.x >> 3, h = threadIdx.x & 7;
  float ss = 0.f, dd = 0.f;
  for(int c=0;c<CC;c++){
    float w = W2[k*256 + h*CC + c];
    ss = fmaf(w, att_s2[h*CC+c], ss);
    dd = fmaf(w, att_d2[h*CC+c], dd);
  }
  ws_s[k*HH+h] = ss;
  ws_d[k*HH+h] = dd;
}

// per-head global max of a[:,h] (n8 = rows*8), into gmax[h] (ordered-int)
__global__ __launch_bounds__(256) void k_gmax(const float* __restrict__ a, int n8,
                                              int* __restrict__ gmax){
  int tid = blockIdx.x*256 + threadIdx.x;
  int lane = threadIdx.x & 63;
  float m = -INFINITY;
  for(int i = tid; i < n8; i += gridDim.x*256) m = fmaxf(m, a[i]);
  #pragma unroll
  for(int msk=8; msk<64; msk<<=1) m = fmaxf(m, __shfl_xor(m, msk));
  if(lane < 8) atomicMax(&gmax[lane], f2ord(m));
}

// adst1[n*8+h] = a_dst_v[x[n]*8+h]  (kills the x->a_dst_v chain in fused1's prologue)
__global__ void k_adst1(const int* __restrict__ x, const float* __restrict__ a_dst_v,
                        float* __restrict__ adst1, int N8){
  int i = blockIdx.x*256 + threadIdx.x;
  if(i >= N8) return;
  adst1[i] = a_dst_v[x[i>>3]*HH + (i&7)];
}

// ------------------- layer-1 vocab-space GEMM (+ gmax1 fold) -------------------
__global__ __launch_bounds__(256,4) void k_gemm1(
    const float* __restrict__ X, const float* __restrict__ W,
    const float* __restrict__ att_s, const float* __restrict__ att_d,
    __half* __restrict__ xl, float* __restrict__ a_src, float* __restrict__ a_dst,
    int* __restrict__ gmax1, int V){
  const int ROWS = 8, FIN = 128;
  __shared__ __align__(16) float xs[ROWS][FIN];
  __shared__ int smax[8];
  int row0 = blockIdx.x*ROWS;
  int tid = threadIdx.x;
  if(tid < 8) smax[tid] = INT_MIN;
  for(int p = tid; p < ROWS*FIN; p += 256){
    int r = p/FIN, kk = p - r*FIN;
    int row = row0 + r;
    xs[r][kk] = (row < V) ? ldntf(X + (size_t)row*FIN + kk) : 0.f;
  }
  __syncthreads();
  float acc[ROWS];
  #pragma unroll
  for(int r=0;r<ROWS;r++) acc[r]=0.f;
  for(int k=0;k<FIN;k++){
    float w = W[(size_t)k*256 + tid];
    #pragma unroll
    for(int r=0;r<ROWS;r++) acc[r] = fmaf(xs[r][k], w, acc[r]);
  }
  float as = att_s[tid], ad = att_d[tid];
  #pragma unroll
  for(int r=0;r<ROWS;r++){
    int n = row0+r;
    float v = acc[r];
    float ps = v*as, pd = v*ad;
    #pragma unroll
    for(int msk=16; msk>=1; msk>>=1){
      ps += __shfl_xor(ps, msk);
      pd += __shfl_xor(pd, msk);
    }
    if(n < V){
      xl[(size_t)n*256 + tid] = __float2half(v);
      if((tid&31)==0){
        int hh = tid>>5;
        a_src[n*HH+hh] = ps;
        a_dst[n*HH+hh] = pd;
        atomicMax(&smax[hh], f2ord(ps));
      }
    }
  }
  __syncthreads();
  if(tid < 8) atomicMax(&gmax1[tid], smax[tid]);
}

// ------------------- layer 1 fused: batched-ILP loop + full-wave epilogue -------------------
__global__ __launch_bounds__(256) void k_fused1(
    const int* __restrict__ off, const int* __restrict__ csr_xv,
    const float* __restrict__ a_src_v, const float* __restrict__ adst1,
    const int* __restrict__ gmax1,
    const __half* __restrict__ xl_v, const float* __restrict__ bias,
    const float* __restrict__ ws_s, const float* __restrict__ ws_d,
    __half* __restrict__ h2h, float* __restrict__ a_src2, float* __restrict__ a_dst2, int N){
  int wid = (int)((blockIdx.x*(size_t)blockDim.x + threadIdx.x) >> 6);
  int lane = threadIdx.x & 63;
  if(wid >= N) return;
  const int start = off[wid], end = off[wid+1];
  const int t = lane >> 3, h = lane & 7;
  const float ad = adst1[wid*HH + h];           // direct coalesced-ish load, no x-> chain
  float mb = ord2f(gmax1[h]) + ad;
  mb = mb > 0.f ? mb : NEG*mb;

  const int h2 = lane >> 3, q = lane & 7, c0 = q*4;
  const __half* xp = xl_v + h2*CC + c0;   // head block at column h2*32 of 256-wide row

  int sv = ldnt(csr_xv + min(start + t, end-1));
  float sraw = a_src_v[sv*HH + h] + ad;
  bool valid = (start + t) < end;

  float eesum = 0.f;
  float4 acc = make_float4(0.f,0.f,0.f,0.f);
  for(int j0 = start; j0 < end; j0 += 8){
    int svn = 0; float srawn = 0.f; bool validn = false;
    if(j0 + 8 < end){
      int jjn = j0 + 8 + t;
      svn = ldnt(csr_xv + min(jjn, end-1));
      srawn = a_src_v[svn*HH + h] + ad;
      validn = jjn < end;
    }
    float v = sraw > 0.f ? sraw : NEG*sraw;
    float ee = valid ? __expf(v - mb) : 0.f;
    eesum += ee;
    float av[8];
    #pragma unroll
    for(int u=0;u<8;u++) av[u] = __shfl(ee, u*8 + h2);
    int s0 = __builtin_amdgcn_readlane(sv, 0);
    int s1 = __builtin_amdgcn_readlane(sv, 8);
    int s2 = __builtin_amdgcn_readlane(sv, 16);
    int s3 = __builtin_amdgcn_readlane(sv, 24);
    int s4 = __builtin_amdgcn_readlane(sv, 32);
    int s5 = __builtin_amdgcn_readlane(sv, 40);
    int s6 = __builtin_amdgcn_readlane(sv, 48);
    int s7 = __builtin_amdgcn_readlane(sv, 56);
    uint2 rv[8];
    rv[0] = *reinterpret_cast<const uint2*>(xp + (size_t)s0*256);
    rv[1] = *reinterpret_cast<const uint2*>(xp + (size_t)s1*256);
    rv[2] = *reinterpret_cast<const uint2*>(xp + (size_t)s2*256);
    rv[3] = *reinterpret_cast<const uint2*>(xp + (size_t)s3*256);
    rv[4] = *reinterpret_cast<const uint2*>(xp + (size_t)s4*256);
    rv[5] = *reinterpret_cast<const uint2*>(xp + (size_t)s5*256);
    rv[6] = *reinterpret_cast<const uint2*>(xp + (size_t)s6*256);
    rv[7] = *reinterpret_cast<const uint2*>(xp + (size_t)s7*256);
    #pragma unroll
    for(int u=0;u<8;u++){
      __half2 ha = *reinterpret_cast<__half2*>(&rv[u].x);
      __half2 hb = *reinterpret_cast<__half2*>(&rv[u].y);
      float2 f01 = __half22float2(ha), f23 = __half22float2(hb);
      acc.x = fmaf(av[u], f01.x, acc.x);
      acc.y = fmaf(av[u], f01.y, acc.y);
      acc.z = fmaf(av[u], f23.x, acc.z);
      acc.w = fmaf(av[u], f23.y, acc.w);
    }
    sv = svn; sraw = srawn; valid = validn;
  }
  #pragma unroll
  for(int msk=8; msk<64; msk<<=1) eesum += __shfl_xor(eesum, msk);
  float is2 = 0.125f / __shfl(eesum, h2);
  acc.x *= is2; acc.y *= is2; acc.z *= is2; acc.w *= is2;
  #pragma unroll
  for(int msk=8; msk<64; msk<<=1){
    acc.x += __shfl_xor(acc.x, msk);
    acc.y += __shfl_xor(acc.y, msk);
    acc.z += __shfl_xor(acc.z, msk);
    acc.w += __shfl_xor(acc.w, msk);
  }
  // every lane holds the reduced channel-quad q total (replicated across h2 groups)
  const float4 b = *reinterpret_cast<const float4*>(bias + c0);
  float4 o = make_float4(fmaxf(acc.x+b.x,0.f), fmaxf(acc.y+b.y,0.f),
                         fmaxf(acc.z+b.z,0.f), fmaxf(acc.w+b.w,0.f));
  if(lane < 8){
    half4 hv;
    hv.a = __floats2half2_rn(o.x, o.y);
    hv.b = __floats2half2_rn(o.z, o.w);
    *reinterpret_cast<half4*>(h2h + (size_t)wid*CC + c0) = hv;
  }
  // layer-2 scores across all 64 lanes: lane (h2,q) computes head-h2 partial over k = 4q..4q+3
  float ps, pd;
  ps  = o.x * ws_s[(4*q+0)*HH + h2];
  ps = fmaf(o.y, ws_s[(4*q+1)*HH + h2], ps);
  ps = fmaf(o.z, ws_s[(4*q+2)*HH + h2], ps);
  ps = fmaf(o.w, ws_s[(4*q+3)*HH + h2], ps);
  pd  = o.x * ws_d[(4*q+0)*HH + h2];
  pd = fmaf(o.y, ws_d[(4*q+1)*HH + h2], pd);
  pd = fmaf(o.z, ws_d[(4*q+2)*HH + h2], pd);
  pd = fmaf(o.w, ws_d[(4*q+3)*HH + h2], pd);
  #pragma unroll
  for(int msk=1; msk<8; msk<<=1){
    ps += __shfl_xor(ps, msk);
    pd += __shfl_xor(pd, msk);
  }
  if(q == 0){
    a_src2[wid*HH + h2] = ps;
    a_dst2[wid*HH + h2] = pd;
  }
}

// ------------------- layer 2 aggregation (single pass, batched-ILP) ----
__global__ __launch_bounds__(256) void k_agg2(
    const int* __restrict__ off, const int* __restrict__ csr_src,
    const float* __restrict__ a_src2, const float* __restrict__ a_dst2,
    const int* __restrict__ gmax2,
    const __half* __restrict__ h2h, float* __restrict__ agg, int N){
  int wid = (int)((blockIdx.x*(size_t)blockDim.x + threadIdx.x) >> 6);
  int lane = threadIdx.x & 63;
  if(wid >= N) return;
  const int start = off[wid], end = off[wid+1];
  const int t = lane >> 3, h = lane & 7;
  const float ad = a_dst2[wid*HH + h];
  float mb = ord2f(gmax2[h]) + ad;
  mb = mb > 0.f ? mb : NEG*mb;

  const int h2 = lane >> 3, k0 = (lane & 7)*4;
  const __half* hp = h2h + k0;   // whole 32-ch row consumed per head; no h2 offset

  int sv = ldnt(csr_src + min(start + t, end-1));
  float sraw = a_src2[sv*HH + h] + ad;
  bool valid = (start + t) < end;

  float eesum = 0.f;
  float4 acc = make_float4(0.f,0.f,0.f,0.f);
  for(int j0 = start; j0 < end; j0 += 8){
    int svn = 0; float srawn = 0.f; bool validn = false;
    if(j0 + 8 < end){
      int jjn = j0 + 8 + t;
      svn = ldnt(csr_src + min(jjn, end-1));
      srawn = a_src2[svn*HH + h] + ad;
      validn = jjn < end;
    }
    float v = sraw > 0.f ? sraw : NEG*sraw;
    float ee = valid ? __expf(v - mb) : 0.f;
    eesum += ee;
    float av[8];
    #pragma unroll
    for(int u=0;u<8;u++) av[u] = __shfl(ee, u*8 + h2);
    int s0 = __builtin_amdgcn_readlane(sv, 0);
    int s1 = __builtin_amdgcn_readlane(sv, 8);
    int s2 = __builtin_amdgcn_readlane(sv, 16);
    int s3 = __builtin_amdgcn_readlane(sv, 24);
    int s4 = __builtin_amdgcn_readlane(sv, 32);
    int s5 = __builtin_amdgcn_readlane(sv, 40);
    int s6 = __builtin_amdgcn_readlane(sv, 48);
    int s7 = __builtin_amdgcn_readlane(sv, 56);
    uint2 rv[8];
    rv[0] = *reinterpret_cast<const uint2*>(hp + (size_t)s0*CC);
    rv[1] = *reinterpret_cast<const uint2*>(hp + (size_t)s1*CC);
    rv[2] = *reinterpret_cast<const uint2*>(hp + (size_t)s2*CC);
    rv[3] = *reinterpret_cast<const uint2*>(hp + (size_t)s3*CC);
    rv[4] = *reinterpret_cast<const uint2*>(hp + (size_t)s4*CC);
    rv[5] = *reinterpret_cast<const uint2*>(hp + (size_t)s5*CC);
    rv[6] = *reinterpret_cast<const uint2*>(hp + (size_t)s6*CC);
    rv[7] = *reinterpret_cast<const uint2*>(hp + (size_t)s7*CC);
    #pragma unroll
    for(int u=0;u<8;u++){
      __half2 ha = *reinterpret_cast<__half2*>(&rv[u].x);
      __half2 hb = *reinterpret_cast<__half2*>(&rv[u].y);
      float2 f01 = __half22float2(ha), f23 = __half22float2(hb);
      acc.x = fmaf(av[u], f01.x, acc.x);
      acc.y = fmaf(av[u], f01.y, acc.y);
      acc.z = fmaf(av[u], f23.x, acc.z);
      acc.w = fmaf(av[u], f23.y, acc.w);
    }
    sv = svn; sraw = srawn; valid = validn;
  }
  #pragma unroll
  for(int msk=8; msk<64; msk<<=1) eesum += __shfl_xor(eesum, msk);
  float is2 = 0.125f / __shfl(eesum, h2);
  f32x4 o; o.x = acc.x*is2; o.y = acc.y*is2; o.z = acc.z*is2; o.w = acc.w*is2;
  stnt4(agg + (size_t)wid*256 + lane*4, o);     // coalesced, nt (read once by trans2)
}

// ------------------- layer 2 transform: z[n,:] = agg[n,:] (per-head) @ W2 + b2 ----
__global__ __launch_bounds__(256) void k_trans2(
    const float* __restrict__ agg, const float* __restrict__ W2,
    const float* __restrict__ b2, float* __restrict__ z, int N){
  __shared__ __align__(16) float aggl[4][256];
  int w = threadIdx.x >> 6, lane = threadIdx.x & 63;
  int wid = (int)(blockIdx.x*4 + w);
  bool active = wid < N;
  f32x4 av = {0.f,0.f,0.f,0.f};
  if(active) av = ldnt4(agg + (size_t)wid*256 + lane*4);
  *reinterpret_cast<f32x4*>(&aggl[w][lane*4]) = av;
  __syncthreads();

  const int ch = lane & 31, part = lane >> 5;
  float p0=0.f, p1=0.f, p2=0.f, p3=0.f;
  #pragma unroll
  for(int hh = 0; hh < 4; ++hh){
    int hq = part*4 + hh;
    const float* wcol = W2 + hq*CC + ch;
    const float* a = &aggl[w][hq*CC];
    #pragma unroll
    for(int k=0;k<CC;k+=4){
      p0 = fmaf(a[k+0], wcol[(size_t)(k+0)*256], p0);
      p1 = fmaf(a[k+1], wcol[(size_t)(k+1)*256], p1);
      p2 = fmaf(a[k+2], wcol[(size_t)(k+2)*256], p2);
      p3 = fmaf(a[k+3], wcol[(size_t)(k+3)*256], p3);
    }
  }
  float p = (p0+p1)+(p2+p3);
  p += __shfl_xor(p, 32);
  if(active && part==0) z[(size_t)wid*CC + ch] = p + b2[ch];
}

__global__ void k_decode(const int* __restrict__ eli, int EL,
                         const float* __restrict__ z, float* __restrict__ out){
  int e = blockIdx.x*blockDim.x + threadIdx.x;
  if(e >= EL) return;
  const float4* za = reinterpret_cast<const float4*>(z + (size_t)ldnt(eli+e)*CC);
  const float4* zb = reinterpret_cast<const float4*>(z + (size_t)ldnt(eli+EL+e)*CC);
  float s = 0.f;
  #pragma unroll
  for(int j=0;j<8;j++){
    float4 u = za[j], v = zb[j];
    s += u.x*v.x + u.y*v.y + u.z*v.z + u.w*v.w;
  }
  out[e] = s;
}

extern "C" void kernel_launch(void* const* d_in, const int* in_sizes, int n_in,
                              void* d_out, int out_size, void* d_ws, size_t ws_size,
                              hipStream_t stream){
  const int*   x   = (const int*)d_in[0];
  const int*   ei  = (const int*)d_in[1];
  const int*   eli = (const int*)d_in[2];
  const float* emb = (const float*)d_in[3];
  const float* W1  = (const float*)d_in[4];
  const float* as1 = (const float*)d_in[5];
  const float* ad1 = (const float*)d_in[6];
  const float* b1  = (const float*)d_in[7];
  const float* W2  = (const float*)d_in[8];
  const float* as2 = (const float*)d_in[9];
  const float* ad2 = (const float*)d_in[10];
  const float* b2  = (const float*)d_in[11];

  const int N  = in_sizes[0];
  const int V  = in_sizes[3]/128;   // 5000
  const int E  = in_sizes[1]/2;
  const int EL = in_sizes[2]/2;
  const int ET = E + N;             // edges + self-loops

  // ---- workspace layout ----
  __half* xl_v = (__half*)d_ws;                         // V*256 halves
  __half* h2h  = xl_v + (size_t)V*256;                  // N*32 halves
  float* a_src_v = (float*)(h2h + (size_t)N*CC);        // V*8
  float* a_dst_v = a_src_v + (size_t)V*HH;              // V*8
  float* adst1   = a_dst_v + (size_t)V*HH;              // N*8
  float* a_src2  = adst1 + (size_t)N*HH;                // N*8
  float* a_dst2  = a_src2 + (size_t)N*HH;               // N*8
  float* z       = a_dst2 + (size_t)N*HH;               // N*32
  float* agg     = z + (size_t)N*CC;                    // N*256
  float* ws_s    = agg + (size_t)N*256;                 // 256
  float* ws_d    = ws_s + 256;                          // 256
  int*   gmax1   = (int*)(ws_d + 256);                  // 8
  int*   gmax2   = gmax1 + 8;                           // 8
  int*   cnt   = gmax2 + 8;                             // N
  int*   off   = cnt + N;                               // N+1
  int*   cur   = off + N + 1;                           // N
  int*   bsum  = cur + N;                               // cdiv(N,256)
  int*   csr   = bsum + ((N+255)/256);                  // ET
  int*   csr_xv= csr + ET;                              // ET

  dim3 blk(256);
  auto cdiv = [](long long a, long long b){ return (unsigned)((a+b-1)/b); };
  const int nb = (int)cdiv(N,256);

  // ---- CSR build ----
  k_init2<<<cdiv(N,256), blk, 0, stream>>>(cnt, gmax1, N);
  k_count<<<cdiv(ET,256), blk, 0, stream>>>(ei, E, ET, cnt);
  k_scan_block<<<nb, blk, 0, stream>>>(cnt, off, bsum, N);
  k_scan_bsum<<<1, blk, 0, stream>>>(bsum, nb, off + N);
  k_scan_add<<<nb, blk, 0, stream>>>(off, bsum, cur, N);
  k_scatter<<<cdiv(ET,256), blk, 0, stream>>>(ei, E, ET, x, cur, csr, csr_xv);

  // ---- small precomputes ----
  k_ws<<<1, blk, 0, stream>>>(W2, as2, ad2, ws_s, ws_d);

  // ---- layer 1 (vocab space) ----
  k_gemm1<<<cdiv(V,8), blk, 0, stream>>>(emb, W1, as1, ad1, xl_v, a_src_v, a_dst_v, gmax1, V);
  k_adst1<<<cdiv((long long)N*HH,256), blk, 0, stream>>>(x, a_dst_v, adst1, N*HH);
  k_fused1<<<cdiv((long long)N*64,256), blk, 0, stream>>>(off, csr_xv, a_src_v, adst1,
                                                          gmax1, xl_v, b1, ws_s, ws_d,
                                                          h2h, a_src2, a_dst2, N);

  // ---- layer 2 ----
  k_gmax<<<64, blk, 0, stream>>>(a_src2, N*HH, gmax2);
  k_agg2<<<cdiv((long long)N*64,256), blk, 0, stream>>>(off, csr, a_src2, a_dst2,
                                                        gmax2, h2h, agg, N);
  k_trans2<<<cdiv(N,4), blk, 0, stream>>>(agg, W2, b2, z, N);

  // ---- decode ----
  k_decode<<<cdiv(EL,256), blk, 0, stream>>>(eli, EL, z, (float*)d_out);
}

// Round 19
// 300.146 us; speedup vs baseline: 3.2289x; 1.1236x over previous
//
#include <hip/hip_runtime.h>
#include <hip/hip_fp16.h>
#include <math.h>
#include <limits.h>

#define HH 8
#define CC 32
#define NEG 0.2f

struct __align__(8) half4 { __half2 a, b; };
typedef float f32x4 __attribute__((ext_vector_type(4)));

__device__ __forceinline__ int ldnt(const int* p){ return __builtin_nontemporal_load(p); }
__device__ __forceinline__ float ldntf(const float* p){ return __builtin_nontemporal_load(p); }
__device__ __forceinline__ int f2ord(float f){ int i=__float_as_int(f); return i>=0? i : i^0x7fffffff; }
__device__ __forceinline__ float ord2f(int i){ return __int_as_float(i>=0? i : i^0x7fffffff); }

__device__ __forceinline__ void edge_sd_nt(const int* __restrict__ ei, int e, int E, int& s, int& d){
  if(e < E){ s = ldnt(ei+e); d = ldnt(ei+E+e); } else { s = e-E; d = s; }
}

// ------------------- init: cnt=0, gmax[16]=INT_MIN -------------------
__global__ void k_init2(int* __restrict__ cnt, int* __restrict__ gmax, int N){
  int i = blockIdx.x*blockDim.x + threadIdx.x;
  if(i < N) cnt[i] = 0;
  if(i < 16) gmax[i] = INT_MIN;
}

__global__ void k_count(const int* __restrict__ ei, int E, int ET, int* __restrict__ cnt){
  int e = blockIdx.x*blockDim.x + threadIdx.x;
  if(e >= ET) return;
  int d = (e < E) ? ldnt(ei+E+e) : e-E;
  atomicAdd(&cnt[d], 1);
}

__global__ __launch_bounds__(256) void k_scan_block(const int* __restrict__ cnt,
                                                    int* __restrict__ off,
                                                    int* __restrict__ bsum, int N){
  int i = blockIdx.x*256 + threadIdx.x;
  int v = (i < N) ? cnt[i] : 0;
  int lane = threadIdx.x & 63;
  int incl = v;
  #pragma unroll
  for(int o=1;o<64;o<<=1){ int u = __shfl_up(incl,o); if(lane>=o) incl += u; }
  __shared__ int wsum[4];
  if(lane==63) wsum[threadIdx.x>>6] = incl;
  __syncthreads();
  int w = threadIdx.x>>6, wadd = 0;
  #pragma unroll
  for(int k=0;k<4;k++) if(k<w) wadd += wsum[k];
  if(i < N) off[i] = wadd + incl - v;
  if(threadIdx.x==255) bsum[blockIdx.x] = wadd + incl;
}

__global__ __launch_bounds__(256) void k_scan_bsum(int* __restrict__ bsum, int nb,
                                                   int* __restrict__ offN){
  int t = threadIdx.x;
  int v = (t < nb) ? bsum[t] : 0;
  int lane = t & 63;
  int incl = v;
  #pragma unroll
  for(int o=1;o<64;o<<=1){ int u = __shfl_up(incl,o); if(lane>=o) incl += u; }
  __shared__ int wsum[4];
  if(lane==63) wsum[t>>6] = incl;
  __syncthreads();
  int w = t>>6, wadd = 0;
  #pragma unroll
  for(int k=0;k<4;k++) if(k<w) wadd += wsum[k];
  if(t < nb) bsum[t] = wadd + incl - v;
  if(t == 255) *offN = wadd + incl;
}

__global__ void k_scan_add(int* __restrict__ off, const int* __restrict__ bsum,
                           int* __restrict__ cur, int N){
  int i = blockIdx.x*256 + threadIdx.x;
  if(i < N){ int v = off[i] + bsum[blockIdx.x]; off[i] = v; cur[i] = v; }
}

__global__ void k_scatter(const int* __restrict__ ei, int E, int ET,
                          const int* __restrict__ x,
                          int* __restrict__ cur, int* __restrict__ csr_src,
                          int* __restrict__ csr_xv){
  int e = blockIdx.x*blockDim.x + threadIdx.x;
  if(e >= ET) return;
  int s,d; edge_sd_nt(ei,e,E,s,d);
  int pos = atomicAdd(&cur[d], 1);
  csr_src[pos] = s;
  csr_xv[pos]  = x[s];
}

// ws_s[k,h] = sum_c W2[k, h*32+c] * att_s2[h,c]   (and ws_d)
__global__ __launch_bounds__(256) void k_ws(const float* __restrict__ W2,
                                            const float* __restrict__ att_s2,
                                            const float* __restrict__ att_d2,
                                            float* __restrict__ ws_s, float* __restrict__ ws_d){
  int k = threadIdx.x >> 3, h = threadIdx.x & 7;
  float ss = 0.f, dd = 0.f;
  for(int c=0;c<CC;c++){
    float w = W2[k*256 + h*CC + c];
    ss = fmaf(w, att_s2[h*CC+c], ss);
    dd = fmaf(w, att_d2[h*CC+c], dd);
  }
  ws_s[k*HH+h] = ss;
  ws_d[k*HH+h] = dd;
}

// per-head global max of a[:,h] (n8 = rows*8), into gmax[h] (ordered-int)
__global__ __launch_bounds__(256) void k_gmax(const float* __restrict__ a, int n8,
                                              int* __restrict__ gmax){
  int tid = blockIdx.x*256 + threadIdx.x;
  int lane = threadIdx.x & 63;
  float m = -INFINITY;
  for(int i = tid; i < n8; i += gridDim.x*256) m = fmaxf(m, a[i]);
  #pragma unroll
  for(int msk=8; msk<64; msk<<=1) m = fmaxf(m, __shfl_xor(m, msk));
  if(lane < 8) atomicMax(&gmax[lane], f2ord(m));
}

// adst1[n*8+h] = a_dst_v[x[n]*8+h]
__global__ void k_adst1(const int* __restrict__ x, const float* __restrict__ a_dst_v,
                        float* __restrict__ adst1, int N8){
  int i = blockIdx.x*256 + threadIdx.x;
  if(i >= N8) return;
  adst1[i] = a_dst_v[x[i>>3]*HH + (i&7)];
}

// ------------------- layer-1 vocab-space GEMM (+ gmax1 fold) -------------------
__global__ __launch_bounds__(256,4) void k_gemm1(
    const float* __restrict__ X, const float* __restrict__ W,
    const float* __restrict__ att_s, const float* __restrict__ att_d,
    __half* __restrict__ xl, float* __restrict__ a_src, float* __restrict__ a_dst,
    int* __restrict__ gmax1, int V){
  const int ROWS = 8, FIN = 128;
  __shared__ __align__(16) float xs[ROWS][FIN];
  __shared__ int smax[8];
  int row0 = blockIdx.x*ROWS;
  int tid = threadIdx.x;
  if(tid < 8) smax[tid] = INT_MIN;
  for(int p = tid; p < ROWS*FIN; p += 256){
    int r = p/FIN, kk = p - r*FIN;
    int row = row0 + r;
    xs[r][kk] = (row < V) ? ldntf(X + (size_t)row*FIN + kk) : 0.f;
  }
  __syncthreads();
  float acc[ROWS];
  #pragma unroll
  for(int r=0;r<ROWS;r++) acc[r]=0.f;
  for(int k=0;k<FIN;k++){
    float w = W[(size_t)k*256 + tid];
    #pragma unroll
    for(int r=0;r<ROWS;r++) acc[r] = fmaf(xs[r][k], w, acc[r]);
  }
  float as = att_s[tid], ad = att_d[tid];
  #pragma unroll
  for(int r=0;r<ROWS;r++){
    int n = row0+r;
    float v = acc[r];
    float ps = v*as, pd = v*ad;
    #pragma unroll
    for(int msk=16; msk>=1; msk>>=1){
      ps += __shfl_xor(ps, msk);
      pd += __shfl_xor(pd, msk);
    }
    if(n < V){
      xl[(size_t)n*256 + tid] = __float2half(v);
      if((tid&31)==0){
        int hh = tid>>5;
        a_src[n*HH+hh] = ps;
        a_dst[n*HH+hh] = pd;
        atomicMax(&smax[hh], f2ord(ps));
      }
    }
  }
  __syncthreads();
  if(tid < 8) atomicMax(&gmax1[tid], smax[tid]);
}

// ------------------- layer 1 fused: batched-ILP loop + full-wave epilogue -------------------
__global__ __launch_bounds__(256) void k_fused1(
    const int* __restrict__ off, const int* __restrict__ csr_xv,
    const float* __restrict__ a_src_v, const float* __restrict__ adst1,
    const int* __restrict__ gmax1,
    const __half* __restrict__ xl_v, const float* __restrict__ bias,
    const float* __restrict__ ws_s, const float* __restrict__ ws_d,
    __half* __restrict__ h2h, float* __restrict__ a_src2, float* __restrict__ a_dst2, int N){
  int wid = (int)((blockIdx.x*(size_t)blockDim.x + threadIdx.x) >> 6);
  int lane = threadIdx.x & 63;
  if(wid >= N) return;
  const int start = off[wid], end = off[wid+1];
  const int t = lane >> 3, h = lane & 7;
  const float ad = adst1[wid*HH + h];
  float mb = ord2f(gmax1[h]) + ad;
  mb = mb > 0.f ? mb : NEG*mb;

  const int h2 = lane >> 3, q = lane & 7, c0 = q*4;
  const __half* xp = xl_v + h2*CC + c0;   // head block at column h2*32 of 256-wide row

  int sv = ldnt(csr_xv + min(start + t, end-1));
  float sraw = a_src_v[sv*HH + h] + ad;
  bool valid = (start + t) < end;

  float eesum = 0.f;
  float4 acc = make_float4(0.f,0.f,0.f,0.f);
  for(int j0 = start; j0 < end; j0 += 8){
    int svn = 0; float srawn = 0.f; bool validn = false;
    if(j0 + 8 < end){
      int jjn = j0 + 8 + t;
      svn = ldnt(csr_xv + min(jjn, end-1));
      srawn = a_src_v[svn*HH + h] + ad;
      validn = jjn < end;
    }
    float v = sraw > 0.f ? sraw : NEG*sraw;
    float ee = valid ? __expf(v - mb) : 0.f;
    eesum += ee;
    float av[8];
    #pragma unroll
    for(int u=0;u<8;u++) av[u] = __shfl(ee, u*8 + h2);
    int s0 = __builtin_amdgcn_readlane(sv, 0);
    int s1 = __builtin_amdgcn_readlane(sv, 8);
    int s2 = __builtin_amdgcn_readlane(sv, 16);
    int s3 = __builtin_amdgcn_readlane(sv, 24);
    int s4 = __builtin_amdgcn_readlane(sv, 32);
    int s5 = __builtin_amdgcn_readlane(sv, 40);
    int s6 = __builtin_amdgcn_readlane(sv, 48);
    int s7 = __builtin_amdgcn_readlane(sv, 56);
    uint2 rv[8];
    rv[0] = *reinterpret_cast<const uint2*>(xp + (size_t)s0*256);
    rv[1] = *reinterpret_cast<const uint2*>(xp + (size_t)s1*256);
    rv[2] = *reinterpret_cast<const uint2*>(xp + (size_t)s2*256);
    rv[3] = *reinterpret_cast<const uint2*>(xp + (size_t)s3*256);
    rv[4] = *reinterpret_cast<const uint2*>(xp + (size_t)s4*256);
    rv[5] = *reinterpret_cast<const uint2*>(xp + (size_t)s5*256);
    rv[6] = *reinterpret_cast<const uint2*>(xp + (size_t)s6*256);
    rv[7] = *reinterpret_cast<const uint2*>(xp + (size_t)s7*256);
    #pragma unroll
    for(int u=0;u<8;u++){
      __half2 ha = *reinterpret_cast<__half2*>(&rv[u].x);
      __half2 hb = *reinterpret_cast<__half2*>(&rv[u].y);
      float2 f01 = __half22float2(ha), f23 = __half22float2(hb);
      acc.x = fmaf(av[u], f01.x, acc.x);
      acc.y = fmaf(av[u], f01.y, acc.y);
      acc.z = fmaf(av[u], f23.x, acc.z);
      acc.w = fmaf(av[u], f23.y, acc.w);
    }
    sv = svn; sraw = srawn; valid = validn;
  }
  #pragma unroll
  for(int msk=8; msk<64; msk<<=1) eesum += __shfl_xor(eesum, msk);
  float is2 = 0.125f / __shfl(eesum, h2);
  acc.x *= is2; acc.y *= is2; acc.z *= is2; acc.w *= is2;
  #pragma unroll
  for(int msk=8; msk<64; msk<<=1){
    acc.x += __shfl_xor(acc.x, msk);
    acc.y += __shfl_xor(acc.y, msk);
    acc.z += __shfl_xor(acc.z, msk);
    acc.w += __shfl_xor(acc.w, msk);
  }
  const float4 b = *reinterpret_cast<const float4*>(bias + c0);
  float4 o = make_float4(fmaxf(acc.x+b.x,0.f), fmaxf(acc.y+b.y,0.f),
                         fmaxf(acc.z+b.z,0.f), fmaxf(acc.w+b.w,0.f));
  if(lane < 8){
    half4 hv;
    hv.a = __floats2half2_rn(o.x, o.y);
    hv.b = __floats2half2_rn(o.z, o.w);
    *reinterpret_cast<half4*>(h2h + (size_t)wid*CC + c0) = hv;
  }
  // layer-2 scores across all 64 lanes: lane (h2,q) -> head-h2 partial over k = 4q..4q+3
  float ps, pd;
  ps  = o.x * ws_s[(4*q+0)*HH + h2];
  ps = fmaf(o.y, ws_s[(4*q+1)*HH + h2], ps);
  ps = fmaf(o.z, ws_s[(4*q+2)*HH + h2], ps);
  ps = fmaf(o.w, ws_s[(4*q+3)*HH + h2], ps);
  pd  = o.x * ws_d[(4*q+0)*HH + h2];
  pd = fmaf(o.y, ws_d[(4*q+1)*HH + h2], pd);
  pd = fmaf(o.z, ws_d[(4*q+2)*HH + h2], pd);
  pd = fmaf(o.w, ws_d[(4*q+3)*HH + h2], pd);
  #pragma unroll
  for(int msk=1; msk<8; msk<<=1){
    ps += __shfl_xor(ps, msk);
    pd += __shfl_xor(pd, msk);
  }
  if(q == 0){
    a_src2[wid*HH + h2] = ps;
    a_dst2[wid*HH + h2] = pd;
  }
}

// ------------------- layer 2 fused: batched-ILP agg + wave-local W2 transform -------------------
// Transform is wave-local: each wave writes its node's agg to LDS and reads it back itself
// (b128 both ways, no __syncthreads). z[n,ch] = sum_h sum_k agg[h][k]*W2[k,h*32+ch] + b2[ch].
__global__ __launch_bounds__(256) void k_fused2(
    const int* __restrict__ off, const int* __restrict__ csr_src,
    const float* __restrict__ a_src2, const float* __restrict__ a_dst2,
    const int* __restrict__ gmax2,
    const __half* __restrict__ h2h, const float* __restrict__ W2,
    const float* __restrict__ b2, float* __restrict__ z, int N){
  __shared__ __align__(16) float aggl[4][256];
  int w = threadIdx.x >> 6;
  int wid = (int)((blockIdx.x*(size_t)blockDim.x + threadIdx.x) >> 6);
  int lane = threadIdx.x & 63;
  if(wid >= N) return;
  const int start = off[wid], end = off[wid+1];
  const int t = lane >> 3, h = lane & 7;
  const float ad = a_dst2[wid*HH + h];
  float mb = ord2f(gmax2[h]) + ad;
  mb = mb > 0.f ? mb : NEG*mb;

  const int h2 = lane >> 3, k0 = (lane & 7)*4;
  const __half* hp = h2h + k0;   // whole 32-ch row consumed per head; no h2 offset

  int sv = ldnt(csr_src + min(start + t, end-1));
  float sraw = a_src2[sv*HH + h] + ad;
  bool valid = (start + t) < end;

  float eesum = 0.f;
  float4 acc = make_float4(0.f,0.f,0.f,0.f);
  for(int j0 = start; j0 < end; j0 += 8){
    int svn = 0; float srawn = 0.f; bool validn = false;
    if(j0 + 8 < end){
      int jjn = j0 + 8 + t;
      svn = ldnt(csr_src + min(jjn, end-1));
      srawn = a_src2[svn*HH + h] + ad;
      validn = jjn < end;
    }
    float v = sraw > 0.f ? sraw : NEG*sraw;
    float ee = valid ? __expf(v - mb) : 0.f;
    eesum += ee;
    float av[8];
    #pragma unroll
    for(int u=0;u<8;u++) av[u] = __shfl(ee, u*8 + h2);
    int s0 = __builtin_amdgcn_readlane(sv, 0);
    int s1 = __builtin_amdgcn_readlane(sv, 8);
    int s2 = __builtin_amdgcn_readlane(sv, 16);
    int s3 = __builtin_amdgcn_readlane(sv, 24);
    int s4 = __builtin_amdgcn_readlane(sv, 32);
    int s5 = __builtin_amdgcn_readlane(sv, 40);
    int s6 = __builtin_amdgcn_readlane(sv, 48);
    int s7 = __builtin_amdgcn_readlane(sv, 56);
    uint2 rv[8];
    rv[0] = *reinterpret_cast<const uint2*>(hp + (size_t)s0*CC);
    rv[1] = *reinterpret_cast<const uint2*>(hp + (size_t)s1*CC);
    rv[2] = *reinterpret_cast<const uint2*>(hp + (size_t)s2*CC);
    rv[3] = *reinterpret_cast<const uint2*>(hp + (size_t)s3*CC);
    rv[4] = *reinterpret_cast<const uint2*>(hp + (size_t)s4*CC);
    rv[5] = *reinterpret_cast<const uint2*>(hp + (size_t)s5*CC);
    rv[6] = *reinterpret_cast<const uint2*>(hp + (size_t)s6*CC);
    rv[7] = *reinterpret_cast<const uint2*>(hp + (size_t)s7*CC);
    #pragma unroll
    for(int u=0;u<8;u++){
      __half2 ha = *reinterpret_cast<__half2*>(&rv[u].x);
      __half2 hb = *reinterpret_cast<__half2*>(&rv[u].y);
      float2 f01 = __half22float2(ha), f23 = __half22float2(hb);
      acc.x = fmaf(av[u], f01.x, acc.x);
      acc.y = fmaf(av[u], f01.y, acc.y);
      acc.z = fmaf(av[u], f23.x, acc.z);
      acc.w = fmaf(av[u], f23.y, acc.w);
    }
    sv = svn; sraw = srawn; valid = validn;
  }
  #pragma unroll
  for(int msk=8; msk<64; msk<<=1) eesum += __shfl_xor(eesum, msk);
  float is2 = 0.125f / __shfl(eesum, h2);
  // lane (h2,q) holds agg[h2][4q..4q+3]; park in LDS (wave-local, no barrier needed)
  f32x4 oo; oo.x = acc.x*is2; oo.y = acc.y*is2; oo.z = acc.z*is2; oo.w = acc.w*is2;
  *reinterpret_cast<f32x4*>(&aggl[w][h2*CC + k0]) = oo;
  // wave-local transform: lane = (part, ch); heads part*4..part*4+3, b128 A-reads
  const int ch = lane & 31, part = lane >> 5;
  const f32x4* arow4 = reinterpret_cast<const f32x4*>(&aggl[w][0]);
  float p0=0.f, p1=0.f, p2=0.f, p3=0.f;
  #pragma unroll
  for(int hh = 0; hh < 4; ++hh){
    int hq = part*4 + hh;
    const float* wcol = W2 + hq*CC + ch;
    #pragma unroll
    for(int k4=0; k4<8; ++k4){
      f32x4 a4 = arow4[hq*8 + k4];
      p0 = fmaf(a4.x, wcol[(size_t)(4*k4+0)*256], p0);
      p1 = fmaf(a4.y, wcol[(size_t)(4*k4+1)*256], p1);
      p2 = fmaf(a4.z, wcol[(size_t)(4*k4+2)*256], p2);
      p3 = fmaf(a4.w, wcol[(size_t)(4*k4+3)*256], p3);
    }
  }
  float p = (p0+p1)+(p2+p3);
  p += __shfl_xor(p, 32);
  if(part==0) z[(size_t)wid*CC + ch] = p + b2[ch];
}

__global__ void k_decode(const int* __restrict__ eli, int EL,
                         const float* __restrict__ z, float* __restrict__ out){
  int e = blockIdx.x*blockDim.x + threadIdx.x;
  if(e >= EL) return;
  const float4* za = reinterpret_cast<const float4*>(z + (size_t)ldnt(eli+e)*CC);
  const float4* zb = reinterpret_cast<const float4*>(z + (size_t)ldnt(eli+EL+e)*CC);
  float s = 0.f;
  #pragma unroll
  for(int j=0;j<8;j++){
    float4 u = za[j], v = zb[j];
    s += u.x*v.x + u.y*v.y + u.z*v.z + u.w*v.w;
  }
  out[e] = s;
}

extern "C" void kernel_launch(void* const* d_in, const int* in_sizes, int n_in,
                              void* d_out, int out_size, void* d_ws, size_t ws_size,
                              hipStream_t stream){
  const int*   x   = (const int*)d_in[0];
  const int*   ei  = (const int*)d_in[1];
  const int*   eli = (const int*)d_in[2];
  const float* emb = (const float*)d_in[3];
  const float* W1  = (const float*)d_in[4];
  const float* as1 = (const float*)d_in[5];
  const float* ad1 = (const float*)d_in[6];
  const float* b1  = (const float*)d_in[7];
  const float* W2  = (const float*)d_in[8];
  const float* as2 = (const float*)d_in[9];
  const float* ad2 = (const float*)d_in[10];
  const float* b2  = (const float*)d_in[11];

  const int N  = in_sizes[0];
  const int V  = in_sizes[3]/128;   // 5000
  const int E  = in_sizes[1]/2;
  const int EL = in_sizes[2]/2;
  const int ET = E + N;             // edges + self-loops

  // ---- workspace layout ----
  __half* xl_v = (__half*)d_ws;                         // V*256 halves
  __half* h2h  = xl_v + (size_t)V*256;                  // N*32 halves
  float* a_src_v = (float*)(h2h + (size_t)N*CC);        // V*8
  float* a_dst_v = a_src_v + (size_t)V*HH;              // V*8
  float* adst1   = a_dst_v + (size_t)V*HH;              // N*8
  float* a_src2  = adst1 + (size_t)N*HH;                // N*8
  float* a_dst2  = a_src2 + (size_t)N*HH;               // N*8
  float* z       = a_dst2 + (size_t)N*HH;               // N*32
  float* ws_s    = z + (size_t)N*CC;                    // 256
  float* ws_d    = ws_s + 256;                          // 256
  int*   gmax1   = (int*)(ws_d + 256);                  // 8
  int*   gmax2   = gmax1 + 8;                           // 8
  int*   cnt   = gmax2 + 8;                             // N
  int*   off   = cnt + N;                               // N+1
  int*   cur   = off + N + 1;                           // N
  int*   bsum  = cur + N;                               // cdiv(N,256)
  int*   csr   = bsum + ((N+255)/256);                  // ET
  int*   csr_xv= csr + ET;                              // ET

  dim3 blk(256);
  auto cdiv = [](long long a, long long b){ return (unsigned)((a+b-1)/b); };
  const int nb = (int)cdiv(N,256);

  // ---- CSR build ----
  k_init2<<<cdiv(N,256), blk, 0, stream>>>(cnt, gmax1, N);
  k_count<<<cdiv(ET,256), blk, 0, stream>>>(ei, E, ET, cnt);
  k_scan_block<<<nb, blk, 0, stream>>>(cnt, off, bsum, N);
  k_scan_bsum<<<1, blk, 0, stream>>>(bsum, nb, off + N);
  k_scan_add<<<nb, blk, 0, stream>>>(off, bsum, cur, N);
  k_scatter<<<cdiv(ET,256), blk, 0, stream>>>(ei, E, ET, x, cur, csr, csr_xv);

  // ---- small precomputes ----
  k_ws<<<1, blk, 0, stream>>>(W2, as2, ad2, ws_s, ws_d);

  // ---- layer 1 (vocab space) ----
  k_gemm1<<<cdiv(V,8), blk, 0, stream>>>(emb, W1, as1, ad1, xl_v, a_src_v, a_dst_v, gmax1, V);
  k_adst1<<<cdiv((long long)N*HH,256), blk, 0, stream>>>(x, a_dst_v, adst1, N*HH);
  k_fused1<<<cdiv((long long)N*64,256), blk, 0, stream>>>(off, csr_xv, a_src_v, adst1,
                                                          gmax1, xl_v, b1, ws_s, ws_d,
                                                          h2h, a_src2, a_dst2, N);

  // ---- layer 2 (agg + wave-local transform fused) ----
  k_gmax<<<64, blk, 0, stream>>>(a_src2, N*HH, gmax2);
  k_fused2<<<cdiv((long long)N*64,256), blk, 0, stream>>>(off, csr, a_src2, a_dst2,
                                                          gmax2, h2h, W2, b2, z, N);

  // ---- decode ----
  k_decode<<<cdiv(EL,256), blk, 0, stream>>>(eli, EL, z, (float*)d_out);
}